// Round 11
// baseline (225.757 us; speedup 1.0000x reference)
//
#include <hip/hip_runtime.h>

typedef unsigned long long u64;
typedef float f32x4 __attribute__((ext_vector_type(4)));

#define BB 16
#define NN 8400
#define GG 100
#define CC 80
#define KTOP 13
#define EPSF 1e-7f
#define INFC 1e8f
#define MAXIN 1024                      // max inside priors per gt (real max ~500)
#define NBIN 16                         // 16x16 spatial bins of 40px over [0,640)

static constexpr size_t kO_LAB  = 0;
static constexpr size_t kO_W    = (size_t)BB * NN;               // 134400
static constexpr size_t kO_BB   = kO_W + (size_t)BB * NN * CC;   // 10886400
static constexpr size_t kO_SC   = kO_BB + (size_t)BB * NN * 4;   // 11424000
static constexpr size_t kO_MET  = kO_SC + (size_t)BB * NN * CC;  // 22176000
static constexpr size_t kO_FG   = kO_MET + (size_t)BB * NN;      // 22310400
static constexpr size_t kO_NUM  = kO_FG + (size_t)BB * NN;       // 22444800
static constexpr size_t kO_DYNW = kO_NUM + CC;                   // 22444880
static constexpr size_t kO_AREA = kO_DYNW + CC;                  // 22444960

// monotone float->uint mapping (total order matching float <)
__device__ __forceinline__ unsigned f2u(float x) {
    unsigned b = __float_as_uint(x);
    return (b & 0x80000000u) ? ~b : (b | 0x80000000u);
}
__device__ __forceinline__ float u2f(unsigned e) {
    return __uint_as_float((e & 0x80000000u) ? (e & 0x7fffffffu) : ~e);
}

// Full pair cost + piou for an INSIDE prior (is_in == flag > 0).
__device__ __forceinline__ void pair_cost_iou_inside(
    float px, float py, float st,
    float p0, float p1, float p2, float p3,
    float g0, float g1, float g2, float g3,
    float lg, float flag,
    float& cost, float& piou)
{
    float gcx = (g0 + g2) * 0.5f, gcy = (g1 + g3) * 0.5f;
    float dx = px - gcx, dy = py - gcy;
    float dist = sqrtf(dx * dx + dy * dy) / st * flag;
    float scp = exp2f((dist - 3.0f) * 3.32192809488736f) * flag;
    float ix1 = fmaxf(p0, g0), iy1 = fmaxf(p1, g1);
    float ix2 = fminf(p2, g2), iy2 = fminf(p3, g3);
    float ow = fmaxf(ix2 - ix1, 0.0f), oh = fmaxf(iy2 - iy1, 0.0f);
    float ov = ow * oh;
    float a1 = (p2 - p0) * (p3 - p1);
    float a2 = (g2 - g0) * (g3 - g1);
    float uni = fmaxf(a1 + a2 - ov, EPSF);
    float iou = ov / uni;
    float ex1 = fminf(p0, g0), ey1 = fminf(p1, g1);
    float ex2 = fmaxf(p2, g2), ey2 = fmaxf(p3, g3);
    float ew = fmaxf(ex2 - ex1, 0.0f), eh = fmaxf(ey2 - ey1, 0.0f);
    float enc = fmaxf(ew * eh, EPSF);
    float giou = iou - (enc - uni) / enc;
    piou = fabsf(giou * flag);
    float iou_cost = -__logf(piou + EPSF) * 3.0f;
    float sig = 1.0f / (1.0f + __expf(-lg));
    float sc = piou - sig;
    float asc = fabsf(sc);
    float bce = fmaxf(lg, 0.0f) - lg * piou + log1pf(__expf(-fabsf(lg)));
    float cls = bce * __expf(asc - 1.0f) * asc;
    cost = cls + iou_cost + scp;
}

// Full pair (any prior) — used by the fused multi-resolve in K2.
__device__ __forceinline__ void pair_cost_iou(
    float px, float py, float st,
    float p0, float p1, float p2, float p3,
    float g0, float g1, float g2, float g3,
    float lg, float flag,
    float& cost, float& piou)
{
    float l = px - g0, t = py - g1, r = g2 - px, d = g3 - py;
    float mn = fminf(fminf(l, t), fminf(r, d));
    float is_in = (mn > 0.0f) ? flag : 0.0f;
    float gcx = (g0 + g2) * 0.5f, gcy = (g1 + g3) * 0.5f;
    float dx = px - gcx, dy = py - gcy;
    float dist = sqrtf(dx * dx + dy * dy) / st * is_in;
    float scp = exp2f((dist - 3.0f) * 3.32192809488736f) * is_in;
    float ix1 = fmaxf(p0, g0), iy1 = fmaxf(p1, g1);
    float ix2 = fminf(p2, g2), iy2 = fminf(p3, g3);
    float ow = fmaxf(ix2 - ix1, 0.0f), oh = fmaxf(iy2 - iy1, 0.0f);
    float ov = ow * oh;
    float a1 = (p2 - p0) * (p3 - p1);
    float a2 = (g2 - g0) * (g3 - g1);
    float uni = fmaxf(a1 + a2 - ov, EPSF);
    float iou = ov / uni;
    float ex1 = fminf(p0, g0), ey1 = fminf(p1, g1);
    float ex2 = fmaxf(p2, g2), ey2 = fmaxf(p3, g3);
    float ew = fmaxf(ex2 - ex1, 0.0f), eh = fmaxf(ey2 - ey1, 0.0f);
    float enc = fmaxf(ew * eh, EPSF);
    float giou = iou - (enc - uni) / enc;
    piou = fabsf(giou * is_in);
    float iou_cost = -__logf(piou + EPSF) * 3.0f;
    float sig = 1.0f / (1.0f + __expf(-lg));
    float sc = piou - sig;
    float asc = fabsf(sc);
    float bce = fmaxf(lg, 0.0f) - lg * piou + log1pf(__expf(-fabsf(lg)));
    float cls = bce * __expf(asc - 1.0f) * asc;
    float cc = cls + iou_cost + scp;
    cost = (is_in > 0.0f) ? cc : INFC;
}

// K0: counting-sort the (b-independent) priors into a 16x16 spatial grid.
// One block, 1024 threads. binned[pos] = (px, py, stride, n-bits).
__global__ __launch_bounds__(1024) void k0_bin(
    const float* __restrict__ priors,
    int*    __restrict__ bin_start,     // 257 ints (exclusive offsets + total)
    float4* __restrict__ binned)        // NN entries
{
    __shared__ int s_cnt[NBIN * NBIN];
    __shared__ int s_scan[NBIN * NBIN];
    __shared__ int s_cur[NBIN * NBIN];
    int tid = threadIdx.x;
    if (tid < NBIN * NBIN) s_cnt[tid] = 0;
    __syncthreads();
    for (int n = tid; n < NN; n += 1024) {
        float px = priors[(size_t)n * 4 + 0];
        float py = priors[(size_t)n * 4 + 1];
        int bx = min(NBIN - 1, (int)(px * 0.025f));   // px >= 0
        int by = min(NBIN - 1, (int)(py * 0.025f));
        atomicAdd(&s_cnt[by * NBIN + bx], 1);
    }
    __syncthreads();
    if (tid < NBIN * NBIN) s_scan[tid] = s_cnt[tid];
    __syncthreads();
    for (int off = 1; off < NBIN * NBIN; off <<= 1) {   // Hillis-Steele inclusive
        int v = 0;
        if (tid < NBIN * NBIN && tid >= off) v = s_scan[tid - off];
        __syncthreads();
        if (tid < NBIN * NBIN) s_scan[tid] += v;
        __syncthreads();
    }
    if (tid < NBIN * NBIN) {
        int ex = s_scan[tid] - s_cnt[tid];              // exclusive
        s_cur[tid] = ex;
        bin_start[tid] = ex;
    }
    if (tid == 0) bin_start[NBIN * NBIN] = NN;
    __syncthreads();
    for (int n = tid; n < NN; n += 1024) {
        float4 p = *reinterpret_cast<const float4*>(priors + (size_t)n * 4);
        int bx = min(NBIN - 1, (int)(p.x * 0.025f));
        int by = min(NBIN - 1, (int)(p.y * 0.025f));
        int pos = atomicAdd(&s_cur[by * NBIN + bx], 1);
        binned[pos] = make_float4(p.x, p.y, p.z, __uint_as_float((unsigned)n));
    }
}

// K1: one workgroup per (b,g). Pass1: strict inside test over only the bins
// overlapping the gt box interior (~300 candidates vs 8400). Pass2: full cost
// on the compacted set. Selection via rank computation (broadcast LDS scans).
// All compares / key order bit-identical to the previously passing version.
__global__ __launch_bounds__(256) void k1_match(
    const float*  __restrict__ pred_bboxes,
    const float*  __restrict__ pred_scores,
    const int*    __restrict__ gt_labels,
    const float*  __restrict__ gt_bboxes,
    const float*  __restrict__ pad_flag,
    const int*    __restrict__ bin_start,
    const float4* __restrict__ binned,
    int*   __restrict__ match_count,
    int*   __restrict__ match_g,
    float* __restrict__ match_iou)
{
    __shared__ int   s_cnt;
    __shared__ int   s_list[MAXIN];     // indices into binned[]
    __shared__ u64   s_kiou[MAXIN];
    __shared__ u64   s_kcost[MAXIN];
    __shared__ unsigned short s_rc[MAXIN];
    __shared__ float s_top[KTOP];

    int bg = blockIdx.x;
    int b = bg / GG, g = bg - b * GG;
    int tid = threadIdx.x;

    float flag = pad_flag[bg];
    if (flag == 0.0f) return;              // block-uniform exit

    if (tid == 0) s_cnt = 0;
    if (tid < KTOP) s_top[tid] = 0.0f;     // pad: top-13 includes 0s when M < 13
    __syncthreads();

    float4 gb = *reinterpret_cast<const float4*>(gt_bboxes + (size_t)bg * 4);

    // Pass 1: candidate bins covering the open box interior (monotone mapping:
    // any prior strictly inside lands in [bx0,bx1]x[by0,by1] after clamping).
    int bx0 = min(NBIN - 1, max(0, (int)floorf(gb.x * 0.025f)));
    int bx1 = min(NBIN - 1, max(0, (int)floorf(gb.z * 0.025f)));
    int by0 = min(NBIN - 1, max(0, (int)floorf(gb.y * 0.025f)));
    int by1 = min(NBIN - 1, max(0, (int)floorf(gb.w * 0.025f)));
    for (int by = by0; by <= by1; ++by) {
        int r0 = bin_start[by * NBIN + bx0];
        int r1 = bin_start[by * NBIN + bx1 + 1];   // row bins are contiguous
        for (int m = r0 + tid; m < r1; m += 256) {
            float4 q = binned[m];
            float mn = fminf(fminf(q.x - gb.x, q.y - gb.y),
                             fminf(gb.z - q.x, gb.w - q.y));
            if (mn > 0.0f) {
                int po = atomicAdd(&s_cnt, 1);
                if (po < MAXIN) s_list[po] = m;
            }
        }
    }
    __syncthreads();
    int M = min(s_cnt, MAXIN);

    if (M == 0) {
        // all costs INFC -> stable-rank winner is prior 0, dyn_k = 1
        if (tid == 0) {
            int idx = b * NN;
            atomicAdd(&match_count[idx], 1);
            match_g[idx]   = g;
            match_iou[idx] = 0.0f;
        }
        return;
    }

    int lab = gt_labels[bg];

    // Pass 2: full cost/piou on compacted set; publish sortable keys to LDS.
    for (int m = tid; m < M; m += 256) {
        float4 q = binned[s_list[m]];
        int n = (int)__float_as_uint(q.w);
        float4 pb = *reinterpret_cast<const float4*>(pred_bboxes + ((size_t)b * NN + n) * 4);
        float lg = pred_scores[((size_t)b * NN + n) * CC + lab];
        float cost, piou;
        pair_cost_iou_inside(q.x, q.y, q.z, pb.x, pb.y, pb.z, pb.w,
                             gb.x, gb.y, gb.z, gb.w, lg, flag, cost, piou);
        s_kiou[m]  = ((u64)f2u(piou) << 32) | (unsigned)n;
        s_kcost[m] = ((u64)f2u(cost) << 32) | (unsigned)n;
    }
    __syncthreads();

    // Rank scan: broadcast reads (all lanes read the same i -> no conflicts).
    for (int m = tid; m < M; m += 256) {
        u64 ki = s_kiou[m];
        u64 kc = s_kcost[m];
        int riou = 0, rcost = 0;
        #pragma unroll 4
        for (int i = 0; i < M; ++i) {
            riou  += (s_kiou[i]  > ki) ? 1 : 0;
            rcost += (s_kcost[i] < kc) ? 1 : 0;
        }
        if (riou < KTOP) s_top[riou] = u2f((unsigned)(ki >> 32));  // unique ranks
        s_rc[m] = (unsigned short)rcost;
    }
    __syncthreads();

    // dyn_k: descending-order sum of top-13 (same order as the reference)
    float ksum = 0.0f;
    #pragma unroll
    for (int r = 0; r < KTOP; ++r) ksum += s_top[r];
    int dyn_k = (int)ksum;                 // trunc; dyn_k <= M (|giou| < 1)
    if (dyn_k < 1) dyn_k = 1;

    // Scatter the dyn_k smallest-cost candidates.
    for (int m = tid; m < M; m += 256) {
        if ((int)s_rc[m] < dyn_k) {
            u64 ki = s_kiou[m];
            int n = (int)(ki & 0xffffffffu);
            int idx = b * NN + n;
            atomicAdd(&match_count[idx], 1);
            match_g[idx]   = g;            // valid only when final count==1
            match_iou[idx] = u2f((unsigned)(ki >> 32));
        }
    }
}

// K2: fused resolve. cnt<=1 via table lookup; cnt>1 handled wave-cooperatively.
__global__ __launch_bounds__(256) void k2_resolve(
    const float* __restrict__ pred_bboxes,
    const float* __restrict__ pred_scores,
    const float* __restrict__ priors,
    const int*   __restrict__ gt_labels,
    const float* __restrict__ gt_bboxes,
    const float* __restrict__ pad_flag,
    const int*   __restrict__ match_count,
    const int*   __restrict__ match_g,
    const float* __restrict__ match_iou,
    int*   __restrict__ r_lab,
    float* __restrict__ r_miou,
    int*   __restrict__ class_num,
    float* __restrict__ out)
{
    int i = blockIdx.x * 256 + threadIdx.x;   // grid exact: 134400/256 = 525
    int lane = threadIdx.x & 63;
    int cnt = match_count[i];
    int b = i / NN;

    int lab = CC;
    float miou = 0.0f;
    float4 bbx = make_float4(0.0f, 0.0f, 0.0f, 0.0f);

    if (cnt == 1) {
        int g = match_g[i];
        int gi = b * GG + g;
        miou = match_iou[i];
        lab = gt_labels[gi];
        bbx = *reinterpret_cast<const float4*>(gt_bboxes + (size_t)gi * 4);
    }

    // wave-cooperative multi resolve: full-cost argmin over 100 gts, 2 slots/lane
    u64 mask = __ballot(cnt > 1);
    while (mask) {
        int src = __builtin_ctzll(mask);
        mask &= mask - 1;
        int ii = (i & ~63) | src;             // wave-aligned (256 % 64 == 0)
        int b2 = ii / NN, n2 = ii - b2 * NN;
        float4 pr = *reinterpret_cast<const float4*>(priors + (size_t)n2 * 4);
        float4 pb = *reinterpret_cast<const float4*>(pred_bboxes + (size_t)ii * 4);
        u64 bk = ~0ull; float bp = 0.0f;
        #pragma unroll
        for (int s = 0; s < 2; ++s) {
            int gg = lane + (s << 6);
            if (gg < GG) {
                int gi = b2 * GG + gg;
                float fl = pad_flag[gi];
                float4 gbx = *reinterpret_cast<const float4*>(gt_bboxes + (size_t)gi * 4);
                int lb = gt_labels[gi];
                float lg = pred_scores[(size_t)ii * CC + lb];
                float cost, piou;
                pair_cost_iou(pr.x, pr.y, pr.z, pb.x, pb.y, pb.z, pb.w,
                              gbx.x, gbx.y, gbx.z, gbx.w, lg, fl, cost, piou);
                u64 k = ((u64)f2u(cost) << 32) | (unsigned)gg;  // tie -> smallest g
                if (k < bk) { bk = k; bp = piou; }
            }
        }
        #pragma unroll
        for (int off = 1; off < 64; off <<= 1) {
            u64 ok = __shfl_xor(bk, off, 64);
            float op = __shfl_xor(bp, off, 64);
            if (ok < bk) { bk = ok; bp = op; }
        }
        if (lane == src) {                    // owner lane keeps the result
            int gw = (int)(bk & 0xffffffffu);
            int gi = b2 * GG + gw;
            lab = gt_labels[gi];
            miou = bp;
            bbx = *reinterpret_cast<const float4*>(gt_bboxes + (size_t)gi * 4);
        }
    }

    bool fg = cnt > 0;
    if (fg) atomicAdd(&class_num[lab], 1);
    r_lab[i]  = lab;
    r_miou[i] = miou;
    out[kO_LAB + i] = (float)lab;
    out[kO_FG  + i] = fg ? 1.0f : 0.0f;
    out[kO_MET + i] = miou;
    *reinterpret_cast<float4*>(out + kO_BB + (size_t)i * 4) = bbx;
}

// K4: fill assigned_scores + weights with nontemporal float4 stores; every
// block recomputes dynw from class_num. Extra blocks: area / NUM / DYNW.
#define K4MAIN ((BB * NN * (CC / 4)) / 256)    // 10500
__global__ __launch_bounds__(256) void k4_fill(
    const int*   __restrict__ r_lab,
    const float* __restrict__ r_miou,
    const int*   __restrict__ class_num,
    const float* __restrict__ gt_area,
    const float* __restrict__ area_rule,
    const float* __restrict__ pad_flag,
    float* __restrict__ out)
{
    __shared__ float s_w[CC];
    int t0 = threadIdx.x;
    if (t0 < 64) {
        int n0 = class_num[t0];
        int n1 = (t0 < CC - 64) ? class_num[t0 + 64] : 0;
        int m = max(n0, n1);
        #pragma unroll
        for (int off = 32; off > 0; off >>= 1) m = max(m, __shfl_down(m, off, 64));
        m = __shfl(m, 0, 64);
        float fm = (float)m;
        s_w[t0] = (n0 > 0) ? fm / fmaxf((float)n0, 1.0f) : 1.0f;
        if (t0 < CC - 64)
            s_w[t0 + 64] = (n1 > 0) ? fm / fmaxf((float)n1, 1.0f) : 1.0f;
    }
    __syncthreads();

    unsigned bid = blockIdx.x;
    if (bid < K4MAIN) {
        unsigned t = bid * 256u + threadIdx.x;   // < 2,688,000 (grid exact)
        unsigned i = t / 20u;                    // const-div -> mulhi
        unsigned cq = (t - i * 20u) * 4u;
        int lab = r_lab[i];
        float miou = r_miou[i];
        bool fg = lab < CC;
        unsigned ulab = (unsigned)lab;
        f32x4 sc, wv;
        sc.x = (ulab == cq + 0u) ? miou : 0.0f;
        sc.y = (ulab == cq + 1u) ? miou : 0.0f;
        sc.z = (ulab == cq + 2u) ? miou : 0.0f;
        sc.w = (ulab == cq + 3u) ? miou : 0.0f;
        wv.x = fg ? s_w[cq + 0u] : 1.0f;
        wv.y = fg ? s_w[cq + 1u] : 1.0f;
        wv.z = fg ? s_w[cq + 2u] : 1.0f;
        wv.w = fg ? s_w[cq + 3u] : 1.0f;
        size_t base = (size_t)i * CC + cq;
        __builtin_nontemporal_store(sc, reinterpret_cast<f32x4*>(out + kO_SC + base));
        __builtin_nontemporal_store(wv, reinterpret_cast<f32x4*>(out + kO_W  + base));
    } else {
        int idx = (int)(bid - K4MAIN) * 256 + threadIdx.x;
        if (idx < 3 * BB * GG) {
            int z = idx / (BB * GG);
            int rem = idx - z * (BB * GG);
            float ga = gt_area[rem];
            float lo = area_rule[z] * area_rule[z];
            float hi = area_rule[z + 1] * area_rule[z + 1];
            bool v = (ga >= lo) && (ga < hi) && (pad_flag[rem] > 0.0f);
            out[kO_AREA + idx] = v ? 1.0f : 0.0f;
        } else if (idx < 3 * BB * GG + CC) {
            int c = idx - 3 * BB * GG;
            out[kO_NUM + c] = (float)class_num[c];
        } else if (idx < 3 * BB * GG + 2 * CC) {
            int c = idx - 3 * BB * GG - CC;
            out[kO_DYNW + c] = s_w[c];
        }
    }
}

extern "C" void kernel_launch(void* const* d_in, const int* in_sizes, int n_in,
                              void* d_out, int out_size, void* d_ws, size_t ws_size,
                              hipStream_t stream)
{
    const float* pred_bboxes = (const float*)d_in[0];
    const float* pred_scores = (const float*)d_in[1];
    const float* priors      = (const float*)d_in[2];
    const int*   gt_labels   = (const int*)d_in[3];
    const float* gt_bboxes   = (const float*)d_in[4];
    const float* pad_flag    = (const float*)d_in[5];
    const float* gt_area     = (const float*)d_in[6];
    const float* area_rule   = (const float*)d_in[7];
    float* out = (float*)d_out;

    // workspace: [match_count BB*NN][class_num CC] zeroed together, then rest
    char* w = (char*)d_ws;
    int*   match_count = (int*)w;    w += (size_t)BB * NN * 4;
    int*   class_num   = (int*)w;    w += (size_t)CC * 4;
    int*   match_g     = (int*)w;    w += (size_t)BB * NN * 4;
    float* match_iou   = (float*)w;  w += (size_t)BB * NN * 4;
    int*   r_lab       = (int*)w;    w += (size_t)BB * NN * 4;
    float* r_miou      = (float*)w;  w += (size_t)BB * NN * 4;
    int*   bin_start   = (int*)w;    w += 1040;            // 257 ints = 1028 B, 16B-pad
    float4* binned     = (float4*)w; w += (size_t)NN * 16;

    (void)hipMemsetAsync(d_ws, 0, (size_t)(BB * NN + CC) * 4, stream);

    k0_bin<<<1, 1024, 0, stream>>>(priors, bin_start, binned);

    k1_match<<<BB * GG, 256, 0, stream>>>(
        pred_bboxes, pred_scores, gt_labels, gt_bboxes, pad_flag,
        bin_start, binned, match_count, match_g, match_iou);

    k2_resolve<<<BB * NN / 256, 256, 0, stream>>>(
        pred_bboxes, pred_scores, priors, gt_labels, gt_bboxes, pad_flag,
        match_count, match_g, match_iou, r_lab, r_miou, class_num, out);

    k4_fill<<<K4MAIN + (3 * BB * GG + 2 * CC + 255) / 256, 256, 0, stream>>>(
        r_lab, r_miou, class_num, gt_area, area_rule, pad_flag, out);
}